// Round 9
// baseline (304.607 us; speedup 1.0000x reference)
//
#include <hip/hip_runtime.h>
#include <hip/hip_bf16.h>
#include <type_traits>

// Problem constants (fixed by the reference)
#define DM   768
#define NH   12
#define HD   64
#define BATCH 8
#define SEQ  1024
#define NROWS (BATCH * SEQ)   // 8192

typedef short bf16x8 __attribute__((ext_vector_type(8)));
typedef float f32x4 __attribute__((ext_vector_type(4)));

// fp32 -> bf16 bits, round-half-up (2 VALU)
__device__ inline unsigned short f2b(float x) {
    union { float f; unsigned int u; } v; v.f = x;
    return (unsigned short)((v.u + 0x8000u) >> 16);
}
// pack two fp32 -> two bf16 (lo in low half): 2 v_add + 1 v_perm
__device__ inline unsigned int f2b2(float lo, float hi) {
    union { float f; unsigned int u; } a, b; a.f = lo; b.f = hi;
    return __builtin_amdgcn_perm(b.u + 0x8000u, a.u + 0x8000u, 0x07060302u);
}
// bf16 bits -> fp32
__device__ inline float b2f(unsigned short u) {
    union { float f; unsigned int x; } v; v.x = ((unsigned int)u) << 16;
    return v.f;
}

// async global->LDS, 16 B per lane; LDS dest = wave-uniform base + lane*16
__device__ inline void gld16(const unsigned short* g, unsigned short* l) {
    __builtin_amdgcn_global_load_lds(
        (const __attribute__((address_space(1))) unsigned int*)g,
        (__attribute__((address_space(3))) unsigned int*)l, 16, 0, 0);
}
__device__ inline void gld16f(const float* g, float* l) {
    __builtin_amdgcn_global_load_lds(
        (const __attribute__((address_space(1))) unsigned int*)g,
        (__attribute__((address_space(3))) unsigned int*)l, 16, 0, 0);
}

// ---------------------------------------------------------------------------
// mm2: PROVEN 2-buffer 128x128 GEMM loop (bf16 A + bf16 W, gld16 both,
// XOR-swizzled LDS, one __syncthreads per K-iter). Local optimum at this
// tile size (counted-vmcnt 3-deep regressed twice: rounds 17 & 20).
// ---------------------------------------------------------------------------
__device__ __forceinline__ void mm2(const unsigned short* __restrict__ A,
                                    const unsigned short* __restrict__ Wt,
                                    int m0, int n0, int t,
                                    unsigned short (*As)[128][32],
                                    unsigned short (*Ws)[128][32],
                                    f32x4 (&acc)[4][4]) {
    const int w = t >> 6, lane = t & 63;
    const int quad = lane >> 4, l16 = lane & 15;
    const int wm = w & 1, wn = w >> 1;
    const int srow = 16 * w + (lane >> 2);
    const int scol = 8 * ((lane & 3) ^ ((lane >> 3) & 3));    // swizzled fetch group
    const int swr = (quad ^ ((l16 >> 1) & 3)) * 8;            // fragment read slot

#pragma unroll
    for (int i = 0; i < 4; ++i)
#pragma unroll
        for (int j = 0; j < 4; ++j) acc[i][j] = (f32x4){0.f, 0.f, 0.f, 0.f};

#pragma unroll
    for (int j = 0; j < 2; ++j) {
        gld16(&A[(size_t)(m0 + srow + 64 * j) * DM + scol], &As[0][16 * w + 64 * j][0]);
        gld16(&Wt[(size_t)(n0 + srow + 64 * j) * DM + scol], &Ws[0][16 * w + 64 * j][0]);
    }
    __syncthreads();

    for (int k0 = 0; k0 < DM; k0 += 32) {
        const int cur = (k0 >> 5) & 1;
        if (k0 + 32 < DM) {
#pragma unroll
            for (int j = 0; j < 2; ++j) {
                gld16(&A[(size_t)(m0 + srow + 64 * j) * DM + k0 + 32 + scol],
                      &As[cur ^ 1][16 * w + 64 * j][0]);
                gld16(&Wt[(size_t)(n0 + srow + 64 * j) * DM + k0 + 32 + scol],
                      &Ws[cur ^ 1][16 * w + 64 * j][0]);
            }
        }
        bf16x8 av[4], bv[4];
#pragma unroll
        for (int i = 0; i < 4; ++i)
            av[i] = *(const bf16x8*)&As[cur][wm * 64 + 16 * i + l16][swr];
#pragma unroll
        for (int i = 0; i < 4; ++i)
            bv[i] = *(const bf16x8*)&Ws[cur][wn * 64 + 16 * i + l16][swr];
        // operand-swapped: fragment row = feature (contiguous in C)
#pragma unroll
        for (int i = 0; i < 4; ++i)
#pragma unroll
            for (int j = 0; j < 4; ++j)
                acc[i][j] = __builtin_amdgcn_mfma_f32_16x16x32_bf16(bv[j], av[i], acc[i][j], 0, 0, 0);
        __syncthreads();
    }
}

// ---------------------------------------------------------------------------
// mm2f (round-22/23): same structure, but A is RAW FP32 staged via gld16f
// (async, no VGPR round-trip — the fix for round-18's failed CVT fusion) and
// converted to bf16 at FRAGMENT-READ time (2x ds_read_b128 + 4 f2b2 per
// fragment, transient regs). Eliminates the aq/ak/av HBM round trip entirely.
// A-tile swizzle at 16B granularity: LDS[row][slot16] holds global slot16 ^
// (row&7) — applied on the global source (gld16 dest must be linear, rule
// #21) and inverted at read. 2 lanes/slot per 16-lane group -> conflict-free.
// ---------------------------------------------------------------------------
__device__ __forceinline__ void mm2f(const float* __restrict__ Af,
                                     const unsigned short* __restrict__ Wt,
                                     int m0, int n0, int t,
                                     float (*As)[128][32],
                                     unsigned short (*Ws)[128][32],
                                     f32x4 (&acc)[4][4]) {
    const int w = t >> 6, lane = t & 63;
    const int quad = lane >> 4, l16 = lane & 15;
    const int wm = w & 1, wn = w >> 1;
    const int srow = 16 * w + (lane >> 2);
    const int scol = 8 * ((lane & 3) ^ ((lane >> 3) & 3));
    const int swr = (quad ^ ((l16 >> 1) & 3)) * 8;
    const int ar = lane >> 3;          // A-staging: row within 8-row wave group
    const int as_ = lane & 7;          // A-staging: 16B slot within 128B row

#pragma unroll
    for (int i = 0; i < 4; ++i)
#pragma unroll
        for (int j = 0; j < 4; ++j) acc[i][j] = (f32x4){0.f, 0.f, 0.f, 0.f};

    auto stage = [&](int k0, int b) {
        // A fp32: wave w, round j covers rows 32j+8w..+8 (1KB); source col
        // pre-swizzled so LDS[r][s] = global cols ((s ^ (r&7))*4 ..+4)
#pragma unroll
        for (int j = 0; j < 4; ++j) {
            const int row = 32 * j + 8 * w + ar;
            gld16f(&Af[(size_t)(m0 + row) * DM + k0 + ((as_ ^ ar) << 2)],
                   &As[b][32 * j + 8 * w][0]);
        }
#pragma unroll
        for (int j = 0; j < 2; ++j)
            gld16(&Wt[(size_t)(n0 + srow + 64 * j) * DM + k0 + scol],
                  &Ws[b][16 * w + 64 * j][0]);
    };

    stage(0, 0);
    __syncthreads();

    for (int k0 = 0; k0 < DM; k0 += 32) {
        const int cur = (k0 >> 5) & 1;
        if (k0 + 32 < DM) stage(k0 + 32, cur ^ 1);
        bf16x8 av[4], bv[4];
#pragma unroll
        for (int i = 0; i < 4; ++i) {
            const int rx = wm * 64 + 16 * i + l16;
            const int hx = l16 & 7;      // rx & 7 (rx ≡ l16 mod 8)
            const float4 f0 = *(const float4*)&As[cur][rx][((2 * quad) ^ hx) << 2];
            const float4 f1 = *(const float4*)&As[cur][rx][((2 * quad + 1) ^ hx) << 2];
            union { unsigned int u[4]; bf16x8 v; } cv;
            cv.u[0] = f2b2(f0.x, f0.y); cv.u[1] = f2b2(f0.z, f0.w);
            cv.u[2] = f2b2(f1.x, f1.y); cv.u[3] = f2b2(f1.z, f1.w);
            av[i] = cv.v;
        }
#pragma unroll
        for (int i = 0; i < 4; ++i)
            bv[i] = *(const bf16x8*)&Ws[cur][wn * 64 + 16 * i + l16][swr];
#pragma unroll
        for (int i = 0; i < 4; ++i)
#pragma unroll
            for (int j = 0; j < 4; ++j)
                acc[i][j] = __builtin_amdgcn_mfma_f32_16x16x32_bf16(bv[j], av[i], acc[i][j], 0, 0, 0);
        __syncthreads();
    }
}

// ---------------------------------------------------------------------------
// Kernel 0 (round-23): WEIGHTS-ONLY prep — fp32->bf16 transpose of the six
// projection weights (z==3 i.e. Wo also emits untransposed wob). Input Q/K/V
// conversion is gone: qkv_gemm stages raw fp32 via mm2f.
// ---------------------------------------------------------------------------
__global__ __launch_bounds__(256) void prep_kernel(const float* __restrict__ w0,
                                                   const float* __restrict__ w1,
                                                   const float* __restrict__ w2,
                                                   const float* __restrict__ w3,
                                                   const float* __restrict__ w4,
                                                   const float* __restrict__ w5,
                                                   unsigned short* __restrict__ wt,
                                                   unsigned short* __restrict__ wob) {
    const int z = blockIdx.z;
    const int t = threadIdx.x;
    __shared__ float tile[32][33];
    const float* W = (z == 0) ? w0 : (z == 1) ? w1 : (z == 2) ? w2
                   : (z == 3) ? w3 : (z == 4) ? w4 : w5;
    unsigned short* Wt = wt + (size_t)z * DM * DM;
    const int n0 = blockIdx.x * 32;
    const int k0 = blockIdx.y * 32;
    const int tx = t & 31;
    const int ty = t >> 5;
    float v[4];
#pragma unroll
    for (int r = 0; r < 4; ++r) {
        v[r] = W[(size_t)(k0 + ty + 8 * r) * DM + n0 + tx];
        tile[ty + 8 * r][tx] = v[r];
    }
    if (z == 3) {
#pragma unroll
        for (int r = 0; r < 4; ++r)
            wob[(size_t)(k0 + ty + 8 * r) * DM + n0 + tx] = f2b(v[r]);
    }
    __syncthreads();
#pragma unroll
    for (int r = 0; r < 4; ++r)
        Wt[(size_t)(n0 + ty + 8 * r) * DM + k0 + tx] = f2b(tile[tx][ty + 8 * r]);
}

// ---------------------------------------------------------------------------
// Kernel 1a: grouped QKV GEMM reading RAW FP32 inputs (mm2f) + aux at y==0
// (dispatched first): x<36 -> wod1 GEMM (bf16 mm2, conflict-free),
// x in [36,52) -> lens reductions. Fused vpart in the V-unit epilogue.
// Q output pre-scaled by 0.125*log2(e) for the exp2 softmax.
// ---------------------------------------------------------------------------
__global__ __launch_bounds__(256) void qkv_gemm(const float* __restrict__ qin,
                                                const float* __restrict__ kin,
                                                const float* __restrict__ vin,
                                                unsigned short* __restrict__ wt,
                                                const unsigned short* __restrict__ wob,
                                                unsigned short* __restrict__ c0,
                                                unsigned short* __restrict__ c1,
                                                unsigned short* __restrict__ c2,
                                                const int* __restrict__ m1,
                                                const int* __restrict__ m2,
                                                int* __restrict__ lens,
                                                float* __restrict__ vp) {
    __shared__ __align__(16) float Asf[2][128][32];          // 32 KB (fp32 A)
    __shared__ __align__(16) unsigned short Wsb[2][128][32]; // 16 KB

    const int t = threadIdx.x;
    const size_t WT = (size_t)DM * DM;

    f32x4 acc[4][4];
    unsigned short* C;
    float cs = 1.0f;
    int m0, n0, g = -1;

    if (blockIdx.y == 0) {
        if (blockIdx.x >= 52) return;
        if (blockIdx.x >= 36) {
            // lens: count of nonzero mask entries per (mask, batch)
            const int bid = blockIdx.x - 36;
            int* redi = (int*)&Asf[0][0][0];
            const int b = bid & 7;
            const int* m = (bid < 8) ? m1 : m2;
            int cnt = 0;
            for (int i = t; i < SEQ; i += 256) cnt += (m[b * SEQ + i] != 0) ? 1 : 0;
            redi[t] = cnt;
            __syncthreads();
            for (int off = 128; off > 0; off >>= 1) {
                if (t < off) redi[t] += redi[t + off];
                __syncthreads();
            }
            if (t == 0) lens[bid] = redi[0];
            return;
        }
        // wod1: out[m][n] = sum_k d1w^T[m][k] * Wo[n][k] = (Wo@d1w)^T
        m0 = (blockIdx.x % 6) * 128;
        n0 = (blockIdx.x / 6) * 128;
        C = wt + 6 * WT;
        mm2(wt + 4 * WT, wob, m0, n0, t,
            (unsigned short (*)[128][32])&Asf[0][0][0], Wsb, acc);
    } else {
        const int yy = blockIdx.y - 1;
        g = yy / 6;
        m0 = blockIdx.x * 128;
        n0 = (yy % 6) * 128;
        const float* Af = (g == 0) ? qin : (g == 1) ? kin : vin;
        C = (g == 0) ? c0 : (g == 1) ? c1 : c2;
        cs = (g == 0) ? 0.18033688f : 1.0f;   // 0.125*log2(e) for Q
        mm2f(Af, wt + (size_t)g * WT, m0, n0, t, Asf, Wsb, acc);
    }

    const int w = t >> 6, lane = t & 63;
    const int quad = lane >> 4, l16 = lane & 15;
    const int wm = w & 1, wn = w >> 1;

#pragma unroll
    for (int i = 0; i < 4; ++i) {
        const int tok = m0 + wm * 64 + 16 * i + l16;
        unsigned short* crow = &C[(size_t)tok * DM + n0 + wn * 64 + quad * 4];
#pragma unroll
        for (int j = 0; j < 4; ++j) {
            uint2 pr;
            pr.x = f2b2(acc[i][j][0] * cs, acc[i][j][1] * cs);
            pr.y = f2b2(acc[i][j][2] * cs, acc[i][j][3] * cs);
            *(uint2*)(crow + 16 * j) = pr;
        }
    }

    if (g == 2) {
        // fused vpart: column sums over this block's 128 tokens (one vp chunk)
        float s2[4][4];
#pragma unroll
        for (int j = 0; j < 4; ++j)
#pragma unroll
            for (int r = 0; r < 4; ++r) {
                float sv = acc[0][j][r] + acc[1][j][r] + acc[2][j][r] + acc[3][j][r];
#pragma unroll
                for (int d = 1; d < 16; d <<= 1) sv += __shfl_xor(sv, d, 64);
                s2[j][r] = sv;
            }
        // lane l16 owns (j,r) = (l16>>2, l16&3); static select (rule 20)
        float mine = 0.f;
#pragma unroll
        for (int j = 0; j < 4; ++j)
#pragma unroll
            for (int r = 0; r < 4; ++r)
                if ((l16 >> 2) == j && (l16 & 3) == r) mine = s2[j][r];
        float* sc = (float*)&Asf[0][0][0];
        const int slot = (wn * 4 + quad) * 16 + l16;
        __syncthreads();
        if (wm == 1) sc[slot] = mine;
        __syncthreads();
        if (wm == 0) {
            const int col = n0 + wn * 64 + 16 * (l16 >> 2) + quad * 4 + (l16 & 3);
            const int bb = m0 >> 10;
            const int chunk = (m0 >> 7) & 7;
            const int hh = col >> 6;
            vp[((size_t)(bb * NH + hh) * 8 + chunk) * 64 + (col & 63)] = mine + sc[slot];
        }
    }
}

// ---------------------------------------------------------------------------
// Kernel 1b: bf16 GEMM 128x128 (mm2); vectorized epilogue.
// ---------------------------------------------------------------------------
template <typename CT>
__global__ __launch_bounds__(256) void gemm_bf(const unsigned short* __restrict__ A,
                                               const unsigned short* __restrict__ Wt,
                                               CT* __restrict__ C,
                                               const float* __restrict__ bias,
                                               const unsigned short* __restrict__ res,
                                               int relu) {
    __shared__ __align__(16) unsigned short As[2][128][32];
    __shared__ __align__(16) unsigned short Ws[2][128][32];

    const int t = threadIdx.x;
    const int m0 = blockIdx.x * 128;
    const int n0 = blockIdx.y * 128;

    f32x4 acc[4][4];
    mm2(A, Wt, m0, n0, t, As, Ws, acc);

    const int w = t >> 6, lane = t & 63;
    const int quad = lane >> 4, l16 = lane & 15;
    const int wm = w & 1, wn = w >> 1;

#pragma unroll
    for (int i = 0; i < 4; ++i) {
        const int tok = m0 + wm * 64 + 16 * i + l16;
#pragma unroll
        for (int j = 0; j < 4; ++j) {
            const int fb = n0 + wn * 64 + 16 * j + quad * 4;
            float cv0 = acc[i][j][0], cv1 = acc[i][j][1];
            float cv2 = acc[i][j][2], cv3 = acc[i][j][3];
            if (bias) {
                const float4 bb = *(const float4*)&bias[fb];
                cv0 += bb.x; cv1 += bb.y; cv2 += bb.z; cv3 += bb.w;
            }
            if (relu) {
                cv0 = fmaxf(cv0, 0.0f); cv1 = fmaxf(cv1, 0.0f);
                cv2 = fmaxf(cv2, 0.0f); cv3 = fmaxf(cv3, 0.0f);
            }
            if (res) {
                const uint2 rr = *(const uint2*)&res[(size_t)tok * DM + fb];
                cv0 += b2f((unsigned short)(rr.x & 0xffffu));
                cv1 += b2f((unsigned short)(rr.x >> 16));
                cv2 += b2f((unsigned short)(rr.y & 0xffffu));
                cv3 += b2f((unsigned short)(rr.y >> 16));
            }
            if constexpr (std::is_same<CT, float>::value) {
                float4 o4; o4.x = cv0; o4.y = cv1; o4.z = cv2; o4.w = cv3;
                *(float4*)&C[(size_t)tok * DM + fb] = o4;
            } else {
                uint2 pr;
                pr.x = f2b2(cv0, cv1);
                pr.y = f2b2(cv2, cv3);
                *(uint2*)&C[(size_t)tok * DM + fb] = pr;
            }
        }
    }
}

// ---------------------------------------------------------------------------
// Kernel 1c: merged mha + ffn-hidden GEMM (mm2).
// ---------------------------------------------------------------------------
__global__ __launch_bounds__(256) void gemm_mh(const unsigned short* __restrict__ A,
                                               const unsigned short* __restrict__ wt,
                                               unsigned short* __restrict__ cm,
                                               unsigned short* __restrict__ ch,
                                               const float* __restrict__ d1b) {
    __shared__ __align__(16) unsigned short As[2][128][32];
    __shared__ __align__(16) unsigned short Ws[2][128][32];

    const int t = threadIdx.x;
    const int unit = blockIdx.y / 6;
    const unsigned short* Wt = wt + (size_t)(unit ? 6 : 3) * DM * DM;
    unsigned short* C = unit ? ch : cm;
    const int m0 = blockIdx.x * 128;
    const int n0 = (blockIdx.y % 6) * 128;

    f32x4 acc[4][4];
    mm2(A, Wt, m0, n0, t, As, Ws, acc);

    const int w = t >> 6, lane = t & 63;
    const int quad = lane >> 4, l16 = lane & 15;
    const int wm = w & 1, wn = w >> 1;

#pragma unroll
    for (int i = 0; i < 4; ++i) {
        const int tok = m0 + wm * 64 + 16 * i + l16;
#pragma unroll
        for (int j = 0; j < 4; ++j) {
            const int fb = n0 + wn * 64 + 16 * j + quad * 4;
            float cv0 = acc[i][j][0], cv1 = acc[i][j][1];
            float cv2 = acc[i][j][2], cv3 = acc[i][j][3];
            if (unit) {
                const float4 bb = *(const float4*)&d1b[fb];
                cv0 = fmaxf(cv0 + bb.x, 0.0f);
                cv1 = fmaxf(cv1 + bb.y, 0.0f);
                cv2 = fmaxf(cv2 + bb.z, 0.0f);
                cv3 = fmaxf(cv3 + bb.w, 0.0f);
            }
            uint2 pr;
            pr.x = f2b2(cv0, cv1);
            pr.y = f2b2(cv2, cv3);
            *(uint2*)&C[(size_t)tok * DM + fb] = pr;
        }
    }
}

// ---------------------------------------------------------------------------
// Kernel 2: MFMA flash attention + mask-aware skipping (round-13/R6 form).
// ---------------------------------------------------------------------------
__global__ __launch_bounds__(256) void attn_mfma(const unsigned short* Q,
                                                 const unsigned short* __restrict__ K,
                                                 const unsigned short* __restrict__ V,
                                                 unsigned short* O,
                                                 const int* __restrict__ lens,
                                                 const float* __restrict__ vp) {
    __shared__ __align__(16) unsigned short Ks[64][72];
    __shared__ __align__(16) unsigned short Vt[64][72];
    __shared__ __align__(16) unsigned short Ps[4][16][72];

    const int t = threadIdx.x;
    const int bid = blockIdx.x;
    const int q0 = (bid & 15) * 64;
    const int h = (bid >> 4) % NH;
    const int b = bid / (16 * NH);
    const int vl1 = lens[b];
    const int vl2 = lens[8 + b];
    const int wid = t >> 6;
    const int lane = t & 63;
    const int quad = lane >> 4;
    const int l16 = lane & 15;
    const size_t vpb = (size_t)(b * NH + h) * 8 * 64;

    if (q0 >= vl2 || vl1 == 0) {
        float vm[4];
#pragma unroll
        for (int ct = 0; ct < 4; ++ct) {
            float s = 0.0f;
#pragma unroll
            for (int c = 0; c < 8; ++c) s += vp[vpb + (size_t)c * 64 + 16 * ct + l16];
            vm[ct] = s * (1.0f / 1024.0f);
        }
#pragma unroll
        for (int r = 0; r < 4; ++r) {
            const size_t row = (size_t)(b * SEQ + q0 + 16 * wid + quad * 4 + r);
#pragma unroll
            for (int ct = 0; ct < 4; ++ct)
                O[row * DM + h * HD + 16 * ct + l16] = f2b(vm[ct]);
        }
        return;
    }

    bf16x8 qa0, qa1;
    {
        const unsigned short* qp =
            &Q[(size_t)(b * SEQ + q0 + 16 * wid + l16) * DM + h * HD + quad * 8];
        qa0 = *(const bf16x8*)qp;
        qa1 = *(const bf16x8*)(qp + 32);
    }

    f32x4 o[4];
#pragma unroll
    for (int ct = 0; ct < 4; ++ct) o[ct] = (f32x4){0.f, 0.f, 0.f, 0.f};
    float suml[4];
    bool rbad[4];
#pragma unroll
    for (int r = 0; r < 4; ++r) {
        suml[r] = 0.0f;
        rbad[r] = (q0 + 16 * wid + quad * 4 + r) >= vl2;
    }

    const int nt = (vl1 + 63) >> 6;

    const int kkr = t >> 3;
    const int khc = (t & 7) * 8;
    const unsigned short* kbase = &K[(size_t)(b * SEQ) * DM + h * HD];
    const unsigned short* vbase = &V[(size_t)(b * SEQ) * DM + h * HD];

    uint4 kr0 = *(const uint4*)&kbase[(size_t)kkr * DM + khc];
    uint4 kr1 = *(const uint4*)&kbase[(size_t)(kkr + 32) * DM + khc];
    uint4 vr0 = *(const uint4*)&vbase[(size_t)lane * DM + wid * 16];
    uint4 vr1 = *(const uint4*)&vbase[(size_t)lane * DM + wid * 16 + 8];

    const int k2 = l16 >> 2;

    for (int tile = 0; tile < nt; ++tile) {
        const int c0 = tile * 64;
        *(uint4*)&Ks[kkr][khc] = kr0;
        *(uint4*)&Ks[kkr + 32][khc] = kr1;
        {
            union { uint4 u; unsigned short s[8]; } va, vb;
            va.u = vr0; vb.u = vr1;
#pragma unroll
            for (int j = 0; j < 8; ++j) Vt[wid * 16 + j][lane] = va.s[j];
#pragma unroll
            for (int j = 0; j < 8; ++j) Vt[wid * 16 + 8 + j][lane] = vb.s[j];
        }
        __syncthreads();

        if (tile < nt - 1) {
            const int c1 = c0 + 64;
            kr0 = *(const uint4*)&kbase[(size_t)(c1 + kkr) * DM + khc];
            kr1 = *(const uint4*)&kbase[(size_t)(c1 + kkr + 32) * DM + khc];
            vr0 = *(const uint4*)&vbase[(size_t)(c1 + lane) * DM + wid * 16];
            vr1 = *(const uint4*)&vbase[(size_t)(c1 + lane) * DM + wid * 16 + 8];
        }

        f32x4 s[4];
#pragma unroll
        for (int ct = 0; ct < 4; ++ct) {
            f32x4 acc = (f32x4){0.f, 0.f, 0.f, 0.f};
            bf16x8 b0v = *(const bf16x8*)&Ks[16 * ct + l16][quad * 8];
            bf16x8 b1v = *(const bf16x8*)&Ks[16 * ct + l16][32 + quad * 8];
            acc = __builtin_amdgcn_mfma_f32_16x16x32_bf16(qa0, b0v, acc, 0, 0, 0);
            acc = __builtin_amdgcn_mfma_f32_16x16x32_bf16(qa1, b1v, acc, 0, 0, 0);
            s[ct] = acc;
        }
#pragma unroll
        for (int ct = 0; ct < 4; ++ct) {
            const bool kok = (c0 + 16 * ct + l16) < vl1;
#pragma unroll
            for (int r = 0; r < 4; ++r) {
                float e = __builtin_amdgcn_exp2f(s[ct][r]);
                float p = kok ? e : 0.0f;
                s[ct][r] = p;
                suml[r] += p;
            }
        }
#pragma unroll
        for (int ct = 0; ct < 4; ++ct) {
            const int gidx = 2 * ct + (l16 >> 3);
            const int c = l16 & 7;
            const int gs = (gidx ^ quad) * 8 + c;
#pragma unroll
            for (int r = 0; r < 4; ++r)
                Ps[wid][quad * 4 + r][gs] = f2b(s[ct][r]);
        }
        bf16x8 pa0 = *(const bf16x8*)&Ps[wid][l16][(quad ^ k2) * 8];
        bf16x8 pa1 = *(const bf16x8*)&Ps[wid][l16][((4 + quad) ^ k2) * 8];
#pragma unroll
        for (int ct = 0; ct < 4; ++ct) {
            bf16x8 vb0 = *(const bf16x8*)&Vt[16 * ct + l16][quad * 8];
            bf16x8 vb1 = *(const bf16x8*)&Vt[16 * ct + l16][32 + quad * 8];
            o[ct] = __builtin_amdgcn_mfma_f32_16x16x32_bf16(pa0, vb0, o[ct], 0, 0, 0);
            o[ct] = __builtin_amdgcn_mfma_f32_16x16x32_bf16(pa1, vb1, o[ct], 0, 0, 0);
        }
        __syncthreads();
    }

#pragma unroll
    for (int d = 1; d < 16; d <<= 1) {
#pragma unroll
        for (int r = 0; r < 4; ++r) suml[r] += __shfl_xor(suml[r], d, 64);
    }

    float vm[4];
    if (rbad[0] || rbad[3]) {
#pragma unroll
        for (int ct = 0; ct < 4; ++ct) {
            float s = 0.0f;
#pragma unroll
            for (int c = 0; c < 8; ++c) s += vp[vpb + (size_t)c * 64 + 16 * ct + l16];
            vm[ct] = s * (1.0f / 1024.0f);
        }
    }
#pragma unroll
    for (int r = 0; r < 4; ++r) {
        const float inv = 1.0f / suml[r];
        const size_t row = (size_t)(b * SEQ + q0 + 16 * wid + quad * 4 + r);
#pragma unroll
        for (int ct = 0; ct < 4; ++ct) {
            const float val = rbad[r] ? vm[ct] : o[ct][r] * inv;
            O[row * DM + h * HD + 16 * ct + l16] = f2b(val);
        }
    }
}

// ---------------------------------------------------------------------------
// Kernel 3: row LayerNorm over D=768, fp32 in/out, IN PLACE on d_out.
// ---------------------------------------------------------------------------
__global__ __launch_bounds__(256) void ln_kernel(float* __restrict__ X,
                                                 const float* __restrict__ g,
                                                 const float* __restrict__ bvec) {
    __shared__ float red[256];
    const int row = blockIdx.x;
    const int t = threadIdx.x;
    float* xr = X + (size_t)row * DM;
    float x0 = xr[t];
    float x1 = xr[t + 256];
    float x2 = xr[t + 512];
    red[t] = x0 + x1 + x2;
    __syncthreads();
    for (int off = 128; off > 0; off >>= 1) {
        if (t < off) red[t] += red[t + off];
        __syncthreads();
    }
    float mu = red[0] * (1.0f / 768.0f);
    __syncthreads();
    float d0 = x0 - mu, d1 = x1 - mu, d2 = x2 - mu;
    red[t] = d0 * d0 + d1 * d1 + d2 * d2;
    __syncthreads();
    for (int off = 128; off > 0; off >>= 1) {
        if (t < off) red[t] += red[t + off];
        __syncthreads();
    }
    float rstd = rsqrtf(red[0] * (1.0f / 768.0f) + 1e-5f);
    xr[t]       = d0 * rstd * g[t]       + bvec[t];
    xr[t + 256] = d1 * rstd * g[t + 256] + bvec[t + 256];
    xr[t + 512] = d2 * rstd * g[t + 512] + bvec[t + 512];
}

// ---------------------------------------------------------------------------
extern "C" void kernel_launch(void* const* d_in, const int* in_sizes, int n_in,
                              void* d_out, int out_size, void* d_ws, size_t ws_size,
                              hipStream_t stream) {
    const float* queries = (const float*)d_in[0];
    const float* keys    = (const float*)d_in[1];
    const float* values  = (const float*)d_in[2];
    const int* mask1 = (const int*)d_in[3];
    const int* mask2 = (const int*)d_in[4];
    const float* Wq  = (const float*)d_in[5];
    const float* Wk  = (const float*)d_in[6];
    const float* Wv  = (const float*)d_in[7];
    const float* Wo  = (const float*)d_in[8];
    const float* d1w = (const float*)d_in[9];
    const float* d1b = (const float*)d_in[10];
    const float* d2w = (const float*)d_in[11];
    const float* d2b = (const float*)d_in[12];
    const float* lng = (const float*)d_in[13];
    const float* lnb = (const float*)d_in[14];

    // workspace: [lens 256B][vp 192KB][b0][b1][b2][Wt x7][wob]  (~48 MB)
    char* ws = (char*)d_ws;
    int* lens = (int*)ws;
    float* vp = (float*)(ws + 256);                                  // 96*8*64 fp32
    const size_t VP = (size_t)96 * 8 * 64 * sizeof(float);
    const size_t NB = (size_t)NROWS * DM * sizeof(unsigned short);   // 12.58 MB
    const size_t WT = (size_t)DM * DM;
    unsigned short* b0 = (unsigned short*)(ws + 256 + VP);
    unsigned short* b1 = (unsigned short*)(ws + 256 + VP + NB);
    unsigned short* b2 = (unsigned short*)(ws + 256 + VP + 2 * NB);
    unsigned short* wt = (unsigned short*)(ws + 256 + VP + 3 * NB);  // 7 x 768*768
    unsigned short* wob = wt + 7 * WT;                               // 768*768 bf16
    float* xout = (float*)d_out;

    // weights-only prep: cvt+transpose (z<6; z==3 also emits wob)
    prep_kernel<<<dim3(24, 24, 6), 256, 0, stream>>>(Wq, Wk, Wv, Wo, d1w, d2w,
                                                     wt, wob);

    // grouped QKV projection reading raw fp32 inputs; aux (wod1 + lens) at y==0
    qkv_gemm<<<dim3(64, 19), 256, 0, stream>>>(queries, keys, values, wt, wob,
                                               b0, b1, b2, mask1, mask2, lens, vp);

    attn_mfma<<<16 * NH * BATCH, 256, 0, stream>>>(b0, b1, b2, b0, lens, vp);  // O over Q

    // merged: mha -> b1, h = relu(attnout@Wod1 + d1b) -> b2
    gemm_mh<<<dim3(64, 12), 256, 0, stream>>>(b0, wt, b1, b2, d1b);

    // x = h @ d2w + d2b + mha -> d_out (fp32)
    gemm_bf<float><<<dim3(64, 6), 256, 0, stream>>>(b2, wt + 5 * WT, xout, d2b, b1, 0);

    ln_kernel<<<NROWS, 256, 0, stream>>>(xout, lng, lnb);  // in place
}

// Round 10
// 292.428 us; speedup vs baseline: 1.0416x; 1.0416x over previous
//
#include <hip/hip_runtime.h>
#include <hip/hip_bf16.h>
#include <type_traits>

// Problem constants (fixed by the reference)
#define DM   768
#define NH   12
#define HD   64
#define BATCH 8
#define SEQ  1024
#define NROWS (BATCH * SEQ)   // 8192

typedef short bf16x8 __attribute__((ext_vector_type(8)));
typedef float f32x4 __attribute__((ext_vector_type(4)));

// fp32 -> bf16 bits, round-half-up (2 VALU)
__device__ inline unsigned short f2b(float x) {
    union { float f; unsigned int u; } v; v.f = x;
    return (unsigned short)((v.u + 0x8000u) >> 16);
}
// pack two fp32 -> two bf16 (lo in low half): 2 v_add + 1 v_perm
__device__ inline unsigned int f2b2(float lo, float hi) {
    union { float f; unsigned int u; } a, b; a.f = lo; b.f = hi;
    return __builtin_amdgcn_perm(b.u + 0x8000u, a.u + 0x8000u, 0x07060302u);
}
// bf16 bits -> fp32
__device__ inline float b2f(unsigned short u) {
    union { float f; unsigned int x; } v; v.x = ((unsigned int)u) << 16;
    return v.f;
}

// async global->LDS, 16 B per lane; LDS dest = wave-uniform base + lane*16
__device__ inline void gld16(const unsigned short* g, unsigned short* l) {
    __builtin_amdgcn_global_load_lds(
        (const __attribute__((address_space(1))) unsigned int*)g,
        (__attribute__((address_space(3))) unsigned int*)l, 16, 0, 0);
}

// ---------------------------------------------------------------------------
// mm2: PROVEN 2-buffer 128x128 GEMM loop (bf16 A + bf16 W, gld16 both,
// XOR-swizzled LDS, one __syncthreads per K-iter). Local optimum at this
// tile size. Closed doors (all measured): counted-vmcnt 3-deep (R17/R20,
// regime-gated to 256^2/8-phase); fp32-A CVT fusion (R18: VGPR/occupancy,
// R22: 128B-row bank-phase conflicts, 3.5M).
// ---------------------------------------------------------------------------
__device__ __forceinline__ void mm2(const unsigned short* __restrict__ A,
                                    const unsigned short* __restrict__ Wt,
                                    int m0, int n0, int t,
                                    unsigned short (*As)[128][32],
                                    unsigned short (*Ws)[128][32],
                                    f32x4 (&acc)[4][4]) {
    const int w = t >> 6, lane = t & 63;
    const int quad = lane >> 4, l16 = lane & 15;
    const int wm = w & 1, wn = w >> 1;
    const int srow = 16 * w + (lane >> 2);
    const int scol = 8 * ((lane & 3) ^ ((lane >> 3) & 3));    // swizzled fetch group
    const int swr = (quad ^ ((l16 >> 1) & 3)) * 8;            // fragment read slot

#pragma unroll
    for (int i = 0; i < 4; ++i)
#pragma unroll
        for (int j = 0; j < 4; ++j) acc[i][j] = (f32x4){0.f, 0.f, 0.f, 0.f};

#pragma unroll
    for (int j = 0; j < 2; ++j) {
        gld16(&A[(size_t)(m0 + srow + 64 * j) * DM + scol], &As[0][16 * w + 64 * j][0]);
        gld16(&Wt[(size_t)(n0 + srow + 64 * j) * DM + scol], &Ws[0][16 * w + 64 * j][0]);
    }
    __syncthreads();

    for (int k0 = 0; k0 < DM; k0 += 32) {
        const int cur = (k0 >> 5) & 1;
        if (k0 + 32 < DM) {
#pragma unroll
            for (int j = 0; j < 2; ++j) {
                gld16(&A[(size_t)(m0 + srow + 64 * j) * DM + k0 + 32 + scol],
                      &As[cur ^ 1][16 * w + 64 * j][0]);
                gld16(&Wt[(size_t)(n0 + srow + 64 * j) * DM + k0 + 32 + scol],
                      &Ws[cur ^ 1][16 * w + 64 * j][0]);
            }
        }
        bf16x8 av[4], bv[4];
#pragma unroll
        for (int i = 0; i < 4; ++i)
            av[i] = *(const bf16x8*)&As[cur][wm * 64 + 16 * i + l16][swr];
#pragma unroll
        for (int i = 0; i < 4; ++i)
            bv[i] = *(const bf16x8*)&Ws[cur][wn * 64 + 16 * i + l16][swr];
        // operand-swapped: fragment row = feature (contiguous in C)
#pragma unroll
        for (int i = 0; i < 4; ++i)
#pragma unroll
            for (int j = 0; j < 4; ++j)
                acc[i][j] = __builtin_amdgcn_mfma_f32_16x16x32_bf16(bv[j], av[i], acc[i][j], 0, 0, 0);
        __syncthreads();
    }
}

// ---------------------------------------------------------------------------
// Kernel 0: streaming prep (R6-best form). Input conversion planes (long
// pole, z<4) dispatch FIRST; weight transposes (z>=4) straggle in parallel.
// Conversion: 4 chunks/block, all 8 float4 loads in flight (MLP depth 8).
// zz==3 (Wo) also emits untransposed wob for the wod1 merged-weight GEMM.
// ---------------------------------------------------------------------------
__global__ __launch_bounds__(256) void prep_kernel(const float* __restrict__ w0,
                                                   const float* __restrict__ w1,
                                                   const float* __restrict__ w2,
                                                   const float* __restrict__ w3,
                                                   const float* __restrict__ w4,
                                                   const float* __restrict__ w5,
                                                   unsigned short* __restrict__ wt,
                                                   unsigned short* __restrict__ wob,
                                                   const float* __restrict__ qin,
                                                   const float* __restrict__ kin,
                                                   const float* __restrict__ vin,
                                                   unsigned short* __restrict__ oq,
                                                   unsigned short* __restrict__ ok,
                                                   unsigned short* __restrict__ ov) {
    const int z = blockIdx.z;
    const int t = threadIdx.x;

    if (z < 4) {
        const int linear = z * 576 + blockIdx.y * 24 + blockIdx.x;
        const int c0 = linear * 4;                 // chunk base (3072%4==0: no straddle)
        const int g = c0 / 3072;
        const int r = c0 % 3072;
        const float* src = (g == 0) ? qin : (g == 1) ? kin : vin;
        unsigned short* dst = (g == 0) ? oq : (g == 1) ? ok : ov;
        const size_t i = ((size_t)r * 256 + t) * 8;
        float4 f[8];
#pragma unroll
        for (int c = 0; c < 4; ++c) {
            f[2 * c]     = ((const float4*)(src + i + (size_t)c * 2048))[0];
            f[2 * c + 1] = ((const float4*)(src + i + (size_t)c * 2048))[1];
        }
#pragma unroll
        for (int c = 0; c < 4; ++c) {
            uint4 p;
            p.x = f2b2(f[2 * c].x, f[2 * c].y);
            p.y = f2b2(f[2 * c].z, f[2 * c].w);
            p.z = f2b2(f[2 * c + 1].x, f[2 * c + 1].y);
            p.w = f2b2(f[2 * c + 1].z, f[2 * c + 1].w);
            *(uint4*)(dst + i + (size_t)c * 2048) = p;
        }
        return;
    }

    // z >= 4: weight fp32 -> bf16 transpose via padded LDS tile
    {
        __shared__ float tile[32][33];
        const int zz = z - 4;
        const float* W = (zz == 0) ? w0 : (zz == 1) ? w1 : (zz == 2) ? w2
                       : (zz == 3) ? w3 : (zz == 4) ? w4 : w5;
        unsigned short* Wt = wt + (size_t)zz * DM * DM;
        const int n0 = blockIdx.x * 32;
        const int k0 = blockIdx.y * 32;
        const int tx = t & 31;
        const int ty = t >> 5;
        float v[4];
#pragma unroll
        for (int r = 0; r < 4; ++r) {
            v[r] = W[(size_t)(k0 + ty + 8 * r) * DM + n0 + tx];
            tile[ty + 8 * r][tx] = v[r];
        }
        if (zz == 3) {
#pragma unroll
            for (int r = 0; r < 4; ++r)
                wob[(size_t)(k0 + ty + 8 * r) * DM + n0 + tx] = f2b(v[r]);
        }
        __syncthreads();
#pragma unroll
        for (int r = 0; r < 4; ++r)
            Wt[(size_t)(n0 + ty + 8 * r) * DM + k0 + tx] = f2b(tile[tx][ty + 8 * r]);
    }
}

// ---------------------------------------------------------------------------
// Kernel 1a: grouped QKV GEMM (mm2) + aux blocks at y==0 (dispatched first):
//   x<36 -> wod1 GEMM (bank-conflict-free), x in [36,52) -> lens reductions.
// Fused vpart: V-unit blocks compute per-(b,h) column partial sums in the
// epilogue (shfl reduce + 512B LDS cross-wave combine) — no vpart kernel.
// Q output pre-scaled by 0.125*log2(e) for the exp2 softmax.
// ---------------------------------------------------------------------------
__global__ __launch_bounds__(256) void qkv_gemm(const unsigned short* __restrict__ aq,
                                                const unsigned short* __restrict__ akk,
                                                const unsigned short* __restrict__ av_,
                                                unsigned short* __restrict__ wt,
                                                const unsigned short* __restrict__ wob,
                                                unsigned short* __restrict__ c0,
                                                unsigned short* __restrict__ c1,
                                                unsigned short* __restrict__ c2,
                                                const int* __restrict__ m1,
                                                const int* __restrict__ m2,
                                                int* __restrict__ lens,
                                                float* __restrict__ vp) {
    __shared__ __align__(16) unsigned short As[2][128][32];
    __shared__ __align__(16) unsigned short Ws[2][128][32];

    const int t = threadIdx.x;
    const size_t WT = (size_t)DM * DM;

    const unsigned short* A;
    const unsigned short* Wop;
    unsigned short* C;
    float cs = 1.0f;
    int m0, n0, g = -1;

    if (blockIdx.y == 0) {
        if (blockIdx.x >= 52) return;
        if (blockIdx.x >= 36) {
            // lens: count of nonzero mask entries per (mask, batch)
            const int bid = blockIdx.x - 36;
            int* redi = (int*)&As[0][0][0];
            const int b = bid & 7;
            const int* m = (bid < 8) ? m1 : m2;
            int cnt = 0;
            for (int i = t; i < SEQ; i += 256) cnt += (m[b * SEQ + i] != 0) ? 1 : 0;
            redi[t] = cnt;
            __syncthreads();
            for (int off = 128; off > 0; off >>= 1) {
                if (t < off) redi[t] += redi[t + off];
                __syncthreads();
            }
            if (t == 0) lens[bid] = redi[0];
            return;
        }
        // wod1: out[m][n] = sum_k d1w^T[m][k] * Wo[n][k] = (Wo@d1w)^T
        A = wt + 4 * WT;
        Wop = wob;
        C = wt + 6 * WT;
        m0 = (blockIdx.x % 6) * 128;
        n0 = (blockIdx.x / 6) * 128;
    } else {
        const int yy = blockIdx.y - 1;
        g = yy / 6;
        m0 = blockIdx.x * 128;
        n0 = (yy % 6) * 128;
        A = (g == 0) ? aq : (g == 1) ? akk : av_;
        Wop = wt + (size_t)g * WT;
        C = (g == 0) ? c0 : (g == 1) ? c1 : c2;
        cs = (g == 0) ? 0.18033688f : 1.0f;   // 0.125*log2(e) for Q
    }

    f32x4 acc[4][4];
    mm2(A, Wop, m0, n0, t, As, Ws, acc);

    const int w = t >> 6, lane = t & 63;
    const int quad = lane >> 4, l16 = lane & 15;
    const int wm = w & 1, wn = w >> 1;

#pragma unroll
    for (int i = 0; i < 4; ++i) {
        const int tok = m0 + wm * 64 + 16 * i + l16;
        unsigned short* crow = &C[(size_t)tok * DM + n0 + wn * 64 + quad * 4];
#pragma unroll
        for (int j = 0; j < 4; ++j) {
            uint2 pr;
            pr.x = f2b2(acc[i][j][0] * cs, acc[i][j][1] * cs);
            pr.y = f2b2(acc[i][j][2] * cs, acc[i][j][3] * cs);
            *(uint2*)(crow + 16 * j) = pr;
        }
    }

    if (g == 2) {
        // fused vpart: column sums over this block's 128 tokens (one vp chunk)
        float s2[4][4];
#pragma unroll
        for (int j = 0; j < 4; ++j)
#pragma unroll
            for (int r = 0; r < 4; ++r) {
                float sv = acc[0][j][r] + acc[1][j][r] + acc[2][j][r] + acc[3][j][r];
#pragma unroll
                for (int d = 1; d < 16; d <<= 1) sv += __shfl_xor(sv, d, 64);
                s2[j][r] = sv;
            }
        // lane l16 owns (j,r) = (l16>>2, l16&3); static select (rule 20)
        float mine = 0.f;
#pragma unroll
        for (int j = 0; j < 4; ++j)
#pragma unroll
            for (int r = 0; r < 4; ++r)
                if ((l16 >> 2) == j && (l16 & 3) == r) mine = s2[j][r];
        float* sc = (float*)&As[0][0][0];
        const int slot = (wn * 4 + quad) * 16 + l16;
        __syncthreads();
        if (wm == 1) sc[slot] = mine;
        __syncthreads();
        if (wm == 0) {
            const int col = n0 + wn * 64 + 16 * (l16 >> 2) + quad * 4 + (l16 & 3);
            const int bb = m0 >> 10;
            const int chunk = (m0 >> 7) & 7;
            const int hh = col >> 6;
            vp[((size_t)(bb * NH + hh) * 8 + chunk) * 64 + (col & 63)] = mine + sc[slot];
        }
    }
}

// ---------------------------------------------------------------------------
// Kernel 1b: bf16 GEMM 128x128 (mm2); vectorized epilogue.
// ---------------------------------------------------------------------------
template <typename CT>
__global__ __launch_bounds__(256) void gemm_bf(const unsigned short* __restrict__ A,
                                               const unsigned short* __restrict__ Wt,
                                               CT* __restrict__ C,
                                               const float* __restrict__ bias,
                                               const unsigned short* __restrict__ res,
                                               int relu) {
    __shared__ __align__(16) unsigned short As[2][128][32];
    __shared__ __align__(16) unsigned short Ws[2][128][32];

    const int t = threadIdx.x;
    const int m0 = blockIdx.x * 128;
    const int n0 = blockIdx.y * 128;

    f32x4 acc[4][4];
    mm2(A, Wt, m0, n0, t, As, Ws, acc);

    const int w = t >> 6, lane = t & 63;
    const int quad = lane >> 4, l16 = lane & 15;
    const int wm = w & 1, wn = w >> 1;

#pragma unroll
    for (int i = 0; i < 4; ++i) {
        const int tok = m0 + wm * 64 + 16 * i + l16;
#pragma unroll
        for (int j = 0; j < 4; ++j) {
            const int fb = n0 + wn * 64 + 16 * j + quad * 4;
            float cv0 = acc[i][j][0], cv1 = acc[i][j][1];
            float cv2 = acc[i][j][2], cv3 = acc[i][j][3];
            if (bias) {
                const float4 bb = *(const float4*)&bias[fb];
                cv0 += bb.x; cv1 += bb.y; cv2 += bb.z; cv3 += bb.w;
            }
            if (relu) {
                cv0 = fmaxf(cv0, 0.0f); cv1 = fmaxf(cv1, 0.0f);
                cv2 = fmaxf(cv2, 0.0f); cv3 = fmaxf(cv3, 0.0f);
            }
            if (res) {
                const uint2 rr = *(const uint2*)&res[(size_t)tok * DM + fb];
                cv0 += b2f((unsigned short)(rr.x & 0xffffu));
                cv1 += b2f((unsigned short)(rr.x >> 16));
                cv2 += b2f((unsigned short)(rr.y & 0xffffu));
                cv3 += b2f((unsigned short)(rr.y >> 16));
            }
            if constexpr (std::is_same<CT, float>::value) {
                float4 o4; o4.x = cv0; o4.y = cv1; o4.z = cv2; o4.w = cv3;
                *(float4*)&C[(size_t)tok * DM + fb] = o4;
            } else {
                uint2 pr;
                pr.x = f2b2(cv0, cv1);
                pr.y = f2b2(cv2, cv3);
                *(uint2*)&C[(size_t)tok * DM + fb] = pr;
            }
        }
    }
}

// ---------------------------------------------------------------------------
// Kernel 1c: merged mha + ffn-hidden GEMM (mm2).
// ---------------------------------------------------------------------------
__global__ __launch_bounds__(256) void gemm_mh(const unsigned short* __restrict__ A,
                                               const unsigned short* __restrict__ wt,
                                               unsigned short* __restrict__ cm,
                                               unsigned short* __restrict__ ch,
                                               const float* __restrict__ d1b) {
    __shared__ __align__(16) unsigned short As[2][128][32];
    __shared__ __align__(16) unsigned short Ws[2][128][32];

    const int t = threadIdx.x;
    const int unit = blockIdx.y / 6;
    const unsigned short* Wt = wt + (size_t)(unit ? 6 : 3) * DM * DM;
    unsigned short* C = unit ? ch : cm;
    const int m0 = blockIdx.x * 128;
    const int n0 = (blockIdx.y % 6) * 128;

    f32x4 acc[4][4];
    mm2(A, Wt, m0, n0, t, As, Ws, acc);

    const int w = t >> 6, lane = t & 63;
    const int quad = lane >> 4, l16 = lane & 15;
    const int wm = w & 1, wn = w >> 1;

#pragma unroll
    for (int i = 0; i < 4; ++i) {
        const int tok = m0 + wm * 64 + 16 * i + l16;
#pragma unroll
        for (int j = 0; j < 4; ++j) {
            const int fb = n0 + wn * 64 + 16 * j + quad * 4;
            float cv0 = acc[i][j][0], cv1 = acc[i][j][1];
            float cv2 = acc[i][j][2], cv3 = acc[i][j][3];
            if (unit) {
                const float4 bb = *(const float4*)&d1b[fb];
                cv0 = fmaxf(cv0 + bb.x, 0.0f);
                cv1 = fmaxf(cv1 + bb.y, 0.0f);
                cv2 = fmaxf(cv2 + bb.z, 0.0f);
                cv3 = fmaxf(cv3 + bb.w, 0.0f);
            }
            uint2 pr;
            pr.x = f2b2(cv0, cv1);
            pr.y = f2b2(cv2, cv3);
            *(uint2*)&C[(size_t)tok * DM + fb] = pr;
        }
    }
}

// ---------------------------------------------------------------------------
// Kernel 2: MFMA flash attention + mask-aware skipping (round-13/R6 form,
// no setprio — R7 A/B suggested it mildly hurts this 4-wave lockstep shape).
// ---------------------------------------------------------------------------
__global__ __launch_bounds__(256) void attn_mfma(const unsigned short* Q,
                                                 const unsigned short* __restrict__ K,
                                                 const unsigned short* __restrict__ V,
                                                 unsigned short* O,
                                                 const int* __restrict__ lens,
                                                 const float* __restrict__ vp) {
    __shared__ __align__(16) unsigned short Ks[64][72];
    __shared__ __align__(16) unsigned short Vt[64][72];
    __shared__ __align__(16) unsigned short Ps[4][16][72];

    const int t = threadIdx.x;
    const int bid = blockIdx.x;
    const int q0 = (bid & 15) * 64;
    const int h = (bid >> 4) % NH;
    const int b = bid / (16 * NH);
    const int vl1 = lens[b];
    const int vl2 = lens[8 + b];
    const int wid = t >> 6;
    const int lane = t & 63;
    const int quad = lane >> 4;
    const int l16 = lane & 15;
    const size_t vpb = (size_t)(b * NH + h) * 8 * 64;

    if (q0 >= vl2 || vl1 == 0) {
        float vm[4];
#pragma unroll
        for (int ct = 0; ct < 4; ++ct) {
            float s = 0.0f;
#pragma unroll
            for (int c = 0; c < 8; ++c) s += vp[vpb + (size_t)c * 64 + 16 * ct + l16];
            vm[ct] = s * (1.0f / 1024.0f);
        }
#pragma unroll
        for (int r = 0; r < 4; ++r) {
            const size_t row = (size_t)(b * SEQ + q0 + 16 * wid + quad * 4 + r);
#pragma unroll
            for (int ct = 0; ct < 4; ++ct)
                O[row * DM + h * HD + 16 * ct + l16] = f2b(vm[ct]);
        }
        return;
    }

    bf16x8 qa0, qa1;
    {
        const unsigned short* qp =
            &Q[(size_t)(b * SEQ + q0 + 16 * wid + l16) * DM + h * HD + quad * 8];
        qa0 = *(const bf16x8*)qp;
        qa1 = *(const bf16x8*)(qp + 32);
    }

    f32x4 o[4];
#pragma unroll
    for (int ct = 0; ct < 4; ++ct) o[ct] = (f32x4){0.f, 0.f, 0.f, 0.f};
    float suml[4];
    bool rbad[4];
#pragma unroll
    for (int r = 0; r < 4; ++r) {
        suml[r] = 0.0f;
        rbad[r] = (q0 + 16 * wid + quad * 4 + r) >= vl2;
    }

    const int nt = (vl1 + 63) >> 6;

    const int kkr = t >> 3;
    const int khc = (t & 7) * 8;
    const unsigned short* kbase = &K[(size_t)(b * SEQ) * DM + h * HD];
    const unsigned short* vbase = &V[(size_t)(b * SEQ) * DM + h * HD];

    uint4 kr0 = *(const uint4*)&kbase[(size_t)kkr * DM + khc];
    uint4 kr1 = *(const uint4*)&kbase[(size_t)(kkr + 32) * DM + khc];
    uint4 vr0 = *(const uint4*)&vbase[(size_t)lane * DM + wid * 16];
    uint4 vr1 = *(const uint4*)&vbase[(size_t)lane * DM + wid * 16 + 8];

    const int k2 = l16 >> 2;

    for (int tile = 0; tile < nt; ++tile) {
        const int c0 = tile * 64;
        *(uint4*)&Ks[kkr][khc] = kr0;
        *(uint4*)&Ks[kkr + 32][khc] = kr1;
        {
            union { uint4 u; unsigned short s[8]; } va, vb;
            va.u = vr0; vb.u = vr1;
#pragma unroll
            for (int j = 0; j < 8; ++j) Vt[wid * 16 + j][lane] = va.s[j];
#pragma unroll
            for (int j = 0; j < 8; ++j) Vt[wid * 16 + 8 + j][lane] = vb.s[j];
        }
        __syncthreads();

        if (tile < nt - 1) {
            const int c1 = c0 + 64;
            kr0 = *(const uint4*)&kbase[(size_t)(c1 + kkr) * DM + khc];
            kr1 = *(const uint4*)&kbase[(size_t)(c1 + kkr + 32) * DM + khc];
            vr0 = *(const uint4*)&vbase[(size_t)(c1 + lane) * DM + wid * 16];
            vr1 = *(const uint4*)&vbase[(size_t)(c1 + lane) * DM + wid * 16 + 8];
        }

        f32x4 s[4];
#pragma unroll
        for (int ct = 0; ct < 4; ++ct) {
            f32x4 acc = (f32x4){0.f, 0.f, 0.f, 0.f};
            bf16x8 b0v = *(const bf16x8*)&Ks[16 * ct + l16][quad * 8];
            bf16x8 b1v = *(const bf16x8*)&Ks[16 * ct + l16][32 + quad * 8];
            acc = __builtin_amdgcn_mfma_f32_16x16x32_bf16(qa0, b0v, acc, 0, 0, 0);
            acc = __builtin_amdgcn_mfma_f32_16x16x32_bf16(qa1, b1v, acc, 0, 0, 0);
            s[ct] = acc;
        }
#pragma unroll
        for (int ct = 0; ct < 4; ++ct) {
            const bool kok = (c0 + 16 * ct + l16) < vl1;
#pragma unroll
            for (int r = 0; r < 4; ++r) {
                float e = __builtin_amdgcn_exp2f(s[ct][r]);
                float p = kok ? e : 0.0f;
                s[ct][r] = p;
                suml[r] += p;
            }
        }
#pragma unroll
        for (int ct = 0; ct < 4; ++ct) {
            const int gidx = 2 * ct + (l16 >> 3);
            const int c = l16 & 7;
            const int gs = (gidx ^ quad) * 8 + c;
#pragma unroll
            for (int r = 0; r < 4; ++r)
                Ps[wid][quad * 4 + r][gs] = f2b(s[ct][r]);
        }
        bf16x8 pa0 = *(const bf16x8*)&Ps[wid][l16][(quad ^ k2) * 8];
        bf16x8 pa1 = *(const bf16x8*)&Ps[wid][l16][((4 + quad) ^ k2) * 8];
#pragma unroll
        for (int ct = 0; ct < 4; ++ct) {
            bf16x8 vb0 = *(const bf16x8*)&Vt[16 * ct + l16][quad * 8];
            bf16x8 vb1 = *(const bf16x8*)&Vt[16 * ct + l16][32 + quad * 8];
            o[ct] = __builtin_amdgcn_mfma_f32_16x16x32_bf16(pa0, vb0, o[ct], 0, 0, 0);
            o[ct] = __builtin_amdgcn_mfma_f32_16x16x32_bf16(pa1, vb1, o[ct], 0, 0, 0);
        }
        __syncthreads();
    }

#pragma unroll
    for (int d = 1; d < 16; d <<= 1) {
#pragma unroll
        for (int r = 0; r < 4; ++r) suml[r] += __shfl_xor(suml[r], d, 64);
    }

    float vm[4];
    if (rbad[0] || rbad[3]) {
#pragma unroll
        for (int ct = 0; ct < 4; ++ct) {
            float s = 0.0f;
#pragma unroll
            for (int c = 0; c < 8; ++c) s += vp[vpb + (size_t)c * 64 + 16 * ct + l16];
            vm[ct] = s * (1.0f / 1024.0f);
        }
    }
#pragma unroll
    for (int r = 0; r < 4; ++r) {
        const float inv = 1.0f / suml[r];
        const size_t row = (size_t)(b * SEQ + q0 + 16 * wid + quad * 4 + r);
#pragma unroll
        for (int ct = 0; ct < 4; ++ct) {
            const float val = rbad[r] ? vm[ct] : o[ct][r] * inv;
            O[row * DM + h * HD + 16 * ct + l16] = f2b(val);
        }
    }
}

// ---------------------------------------------------------------------------
// Kernel 3: row LayerNorm over D=768, fp32 in/out, IN PLACE on d_out.
// Round-24: 192 threads (3 waves, all lanes active), float4 I/O, per-wave
// __shfl_xor reduction + 3-word LDS combine — 2 barriers total (was 16
// tree-barrier iterations with 64 idle lanes).
// ---------------------------------------------------------------------------
__global__ __launch_bounds__(192) void ln_kernel(float* __restrict__ X,
                                                 const float* __restrict__ g,
                                                 const float* __restrict__ bvec) {
    __shared__ float part[3];
    __shared__ float part2[3];
    const int row = blockIdx.x;
    const int t = threadIdx.x;
    float* xr = X + (size_t)row * DM;
    const float4 x = *(const float4*)&xr[t * 4];
    float s = x.x + x.y + x.z + x.w;
#pragma unroll
    for (int d = 1; d < 64; d <<= 1) s += __shfl_xor(s, d, 64);
    if ((t & 63) == 0) part[t >> 6] = s;
    __syncthreads();
    const float mu = (part[0] + part[1] + part[2]) * (1.0f / 768.0f);
    const float d0 = x.x - mu, d1 = x.y - mu, d2 = x.z - mu, d3 = x.w - mu;
    float v = d0 * d0 + d1 * d1 + d2 * d2 + d3 * d3;
#pragma unroll
    for (int d = 1; d < 64; d <<= 1) v += __shfl_xor(v, d, 64);
    if ((t & 63) == 0) part2[t >> 6] = v;
    __syncthreads();
    const float rstd = rsqrtf((part2[0] + part2[1] + part2[2]) * (1.0f / 768.0f) + 1e-5f);
    const float4 gg = *(const float4*)&g[t * 4];
    const float4 bb = *(const float4*)&bvec[t * 4];
    float4 o4;
    o4.x = d0 * rstd * gg.x + bb.x;
    o4.y = d1 * rstd * gg.y + bb.y;
    o4.z = d2 * rstd * gg.z + bb.z;
    o4.w = d3 * rstd * gg.w + bb.w;
    *(float4*)&xr[t * 4] = o4;
}

// ---------------------------------------------------------------------------
extern "C" void kernel_launch(void* const* d_in, const int* in_sizes, int n_in,
                              void* d_out, int out_size, void* d_ws, size_t ws_size,
                              hipStream_t stream) {
    const float* queries = (const float*)d_in[0];
    const float* keys    = (const float*)d_in[1];
    const float* values  = (const float*)d_in[2];
    const int* mask1 = (const int*)d_in[3];
    const int* mask2 = (const int*)d_in[4];
    const float* Wq  = (const float*)d_in[5];
    const float* Wk  = (const float*)d_in[6];
    const float* Wv  = (const float*)d_in[7];
    const float* Wo  = (const float*)d_in[8];
    const float* d1w = (const float*)d_in[9];
    const float* d1b = (const float*)d_in[10];
    const float* d2w = (const float*)d_in[11];
    const float* d2b = (const float*)d_in[12];
    const float* lng = (const float*)d_in[13];
    const float* lnb = (const float*)d_in[14];

    // workspace: [lens 256B][vp 192KB][b0][b1][b2][Wt x7][aq][ak][av][wob] (~86 MB)
    char* ws = (char*)d_ws;
    int* lens = (int*)ws;
    float* vp = (float*)(ws + 256);                                  // 96*8*64 fp32
    const size_t VP = (size_t)96 * 8 * 64 * sizeof(float);
    const size_t NB = (size_t)NROWS * DM * sizeof(unsigned short);   // 12.58 MB
    const size_t WT = (size_t)DM * DM;
    unsigned short* b0 = (unsigned short*)(ws + 256 + VP);
    unsigned short* b1 = (unsigned short*)(ws + 256 + VP + NB);
    unsigned short* b2 = (unsigned short*)(ws + 256 + VP + 2 * NB);
    unsigned short* wt = (unsigned short*)(ws + 256 + VP + 3 * NB);  // 7 x 768*768
    unsigned short* aq = (unsigned short*)(ws + 256 + VP + 3 * NB + 7 * WT * sizeof(unsigned short));
    unsigned short* ak = aq + (size_t)NROWS * DM;
    unsigned short* av = ak + (size_t)NROWS * DM;
    unsigned short* wob = av + (size_t)NROWS * DM;                   // 768*768 bf16
    float* xout = (float*)d_out;

    // streaming prep: input cvt (z<4, dispatched first), weight cvt+transpose (z>=4)
    prep_kernel<<<dim3(24, 24, 10), 256, 0, stream>>>(Wq, Wk, Wv, Wo, d1w, d2w,
                                                      wt, wob, queries, keys, values,
                                                      aq, ak, av);

    // grouped QKV projection + fused vp column sums; aux (wod1 + lens) at y==0
    qkv_gemm<<<dim3(64, 19), 256, 0, stream>>>(aq, ak, av, wt, wob, b0, b1, b2,
                                               mask1, mask2, lens, vp);

    attn_mfma<<<16 * NH * BATCH, 256, 0, stream>>>(b0, b1, b2, b0, lens, vp);  // O over Q

    // merged: mha -> b1, h = relu(attnout@Wod1 + d1b) -> b2
    gemm_mh<<<dim3(64, 12), 256, 0, stream>>>(b0, wt, b1, b2, d1b);

    // x = h @ d2w + d2b + mha -> d_out (fp32)
    gemm_bf<float><<<dim3(64, 6), 256, 0, stream>>>(b2, wt + 5 * WT, xout, d2b, b1, 0);

    ln_kernel<<<NROWS, 192, 0, stream>>>(xout, lng, lnb);  // in place
}